// Round 4
// baseline (501.654 us; speedup 1.0000x reference)
//
#include <hip/hip_runtime.h>
#include <hip/hip_bf16.h>

// SiglipSdpaAttention: B=32, N=1024, D=1152, R=4, M=N/R=256.
// Algebra: merge commutes with projections; softmax drops row-constant terms.
//   S = x·(Wq^T Wk)·x_m^T + c[m],  c = x_m·(Wk^T bq)   (bk terms drop)
//   out = P·(x_m·(Wo Wv)^T + Wo bv) + bo
// Pipeline (~88 GFLOP):
//   [U | VW] = x_m @ [Wqk ; Wvo]^T + [0 | Wo·bv]
//   fused: P = softmax((x@U^T + c)/sqrt(D)); out = P@VW + bo  (P stays in LDS)
// bf16 MFMA 16x16x32, global_load_lds width-16, XCD swizzle for panel locality.

typedef __bf16 bf16;
typedef __attribute__((ext_vector_type(8))) __bf16 bf16x8;
typedef __attribute__((ext_vector_type(4))) __bf16 bf16x4;
typedef __attribute__((ext_vector_type(4))) float f32x4;

#define GAS __attribute__((address_space(1)))
#define LAS __attribute__((address_space(3)))

__device__ __forceinline__ void async_copy16(const void* g, void* s) {
    __builtin_amdgcn_global_load_lds((GAS unsigned int*)g, (LAS unsigned int*)s, 16, 0, 0);
}

// C = A * B^T (+bias) * scale. A:[M x K] rowmajor (lda), B:[N x K] rowmajor (ldb),
// C:[M x N] (ldc). Tile 128x128, BK=32, 256 thr = 4 waves (2x2 of 64x64).
template <typename OutT, bool HAS_BIAS>
__global__ __launch_bounds__(256) void gemm_bt(
    const bf16* __restrict__ A, const bf16* __restrict__ B,
    const float* __restrict__ bias, OutT* __restrict__ C,
    int N, int K, int lda, int ldb, int ldc, float scale,
    long sAb, long sBb, long sCb) {
    __shared__ __align__(16) bf16 As[128 * 32];
    __shared__ __align__(16) bf16 Bs[128 * 32];
    const int tid  = threadIdx.x;
    const int wave = tid >> 6;
    const int lane = tid & 63;
    const int quad = lane >> 4;
    const int l16  = lane & 15;
    const int wM   = (wave >> 1) * 64;
    const int wN   = (wave & 1) * 64;

    // XCD swizzle: all x-tiles of an A-panel on one XCD (A fetched once/panel).
    int bx = blockIdx.x, by = blockIdx.y;
    const int nbx = gridDim.x, nby = gridDim.y;
    if (((nby & 7) == 0) && (nbx % 9 == 0)) {
        int lid = by * nbx + bx;
        int xcd = lid & 7;
        int s   = lid >> 3;
        int Pn  = nby >> 3;
        int gsz = 9 * Pn;
        int g   = s / gsz;
        int rem = s - g * gsz;
        int p   = rem / 9;
        by = p * 8 + xcd;
        bx = g * 9 + (rem - p * 9);
    }

    const long zb = blockIdx.z;
    A += zb * sAb;
    B += zb * sBb;
    C += zb * sCb;

    const int rowBase = by * 128;
    const int colBase = bx * 128;

    const int g0 = wave * 64 + lane;
    const int r0 = g0 >> 2;
    const int c0 = (g0 & 3) * 8;
    const bf16* a0 = A + (long)(rowBase + r0) * lda + c0;
    const bf16* a1 = A + (long)(rowBase + 64 + r0) * lda + c0;
    const bf16* b0 = B + (long)(colBase + r0) * ldb + c0;
    const bf16* b1 = B + (long)(colBase + 64 + r0) * ldb + c0;
    char* lA0 = (char*)As + wave * 1024;
    char* lA1 = (char*)As + 4096 + wave * 1024;
    char* lB0 = (char*)Bs + wave * 1024;
    char* lB1 = (char*)Bs + 4096 + wave * 1024;

    f32x4 acc[4][4] = {};

    const int kt = K >> 5;
    for (int k = 0; k < kt; ++k) {
        __syncthreads();
        async_copy16(a0, lA0);
        async_copy16(a1, lA1);
        async_copy16(b0, lB0);
        async_copy16(b1, lB1);
        a0 += 32; a1 += 32; b0 += 32; b1 += 32;
        __syncthreads();
        bf16x8 af[4], bfv[4];
#pragma unroll
        for (int t = 0; t < 4; ++t) {
            af[t]  = *(const bf16x8*)(As + (wM + t * 16 + l16) * 32 + quad * 8);
            bfv[t] = *(const bf16x8*)(Bs + (wN + t * 16 + l16) * 32 + quad * 8);
        }
#pragma unroll
        for (int mt = 0; mt < 4; ++mt)
#pragma unroll
            for (int nt = 0; nt < 4; ++nt)
                acc[mt][nt] = __builtin_amdgcn_mfma_f32_16x16x32_bf16(
                    af[mt], bfv[nt], acc[mt][nt], 0, 0, 0);
    }

    // C/D layout: col = lane&15, row = quad*4 + reg  [m89/m91]
#pragma unroll
    for (int mt = 0; mt < 4; ++mt) {
        const int row = rowBase + wM + mt * 16 + quad * 4;
#pragma unroll
        for (int nt = 0; nt < 4; ++nt) {
            const int col = colBase + wN + nt * 16 + l16;
            const float bv = HAS_BIAS ? bias[col] : 0.0f;
#pragma unroll
            for (int r = 0; r < 4; ++r) {
                float v = acc[mt][nt][r] * scale + bv;
                C[(long)(row + r) * ldc + col] = (OutT)v;
            }
        }
    }
}

// Fused attention: per block one batch b, 64 Q-rows. 256 thr = 4 waves.
// Phase 1 (scores): S[64x256] = x@U^T + c[m]; wave w covers cols w*64.
// Phase 2: softmax across 256 cols (cross-wave via LDS red arrays); P -> LDS.
// Phase 3 (PV): out[64x1152] = P@VWT^T + bo, d in 9 chunks of 128.
__global__ __launch_bounds__(256) void fused_attn_k(
    const bf16* __restrict__ X, const bf16* __restrict__ UVW,
    const bf16* __restrict__ VWT, const float* __restrict__ cvec,
    const float* __restrict__ bo, float* __restrict__ out) {
    __shared__ __align__(16) bf16 As[64 * 32];    // 4KB
    __shared__ __align__(16) bf16 Bs[256 * 32];   // 16KB (scores U-tile; PV VWT-tile 128x32)
    __shared__ __align__(16) bf16 Ps[64][264];    // 33.8KB, pad 8 vs 256
    __shared__ float red[64][4];
    __shared__ float red2[64][4];
    const int tid  = threadIdx.x;
    const int wave = tid >> 6;
    const int lane = tid & 63;
    const int quad = lane >> 4;
    const int l16  = lane & 15;
    const int wN   = wave * 64;

    // swizzle: all 16 row-tiles of a batch on one XCD
    int bx = blockIdx.x, by = blockIdx.y;
    {
        int lid = by * 16 + bx;
        int xcd = lid & 7;
        int s   = lid >> 3;       // 0..63
        by = (s >> 4) * 8 + xcd;  // batch
        bx = s & 15;              // row tile
    }
    const long b = by;
    const bf16* Abase = X + (b * 1024 + (long)bx * 64) * 1152;
    const bf16* Bbase = UVW + b * 256 * 2304;  // U part, stride 2304

    const int ra = tid >> 2, ca = (tid & 3) * 8;
    const bf16* aptr = Abase + (long)ra * 1152 + ca;
    const bf16* bptr = Bbase + (long)ra * 2304 + ca;
    char* lA = (char*)As + wave * 1024;
    char* lB = (char*)Bs + wave * 1024;

    f32x4 acc[4][4] = {};
#pragma unroll 1
    for (int k = 0; k < 36; ++k) {
        __syncthreads();
        async_copy16(aptr, lA);
        async_copy16(bptr,               lB);
        async_copy16(bptr +  64 * 2304,  lB + 4096);
        async_copy16(bptr + 128 * 2304,  lB + 8192);
        async_copy16(bptr + 192 * 2304,  lB + 12288);
        aptr += 32; bptr += 32;
        __syncthreads();
        bf16x8 af[4], bfv[4];
#pragma unroll
        for (int t = 0; t < 4; ++t) {
            af[t]  = *(const bf16x8*)(As + (t * 16 + l16) * 32 + quad * 8);
            bfv[t] = *(const bf16x8*)(Bs + (wN + t * 16 + l16) * 32 + quad * 8);
        }
#pragma unroll
        for (int mt = 0; mt < 4; ++mt)
#pragma unroll
            for (int nt = 0; nt < 4; ++nt)
                acc[mt][nt] = __builtin_amdgcn_mfma_f32_16x16x32_bf16(
                    af[mt], bfv[nt], acc[mt][nt], 0, 0, 0);
    }

    // + c[m]
    float cv[4];
#pragma unroll
    for (int nt = 0; nt < 4; ++nt) cv[nt] = cvec[b * 256 + wN + nt * 16 + l16];
#pragma unroll
    for (int mt = 0; mt < 4; ++mt)
#pragma unroll
        for (int nt = 0; nt < 4; ++nt)
#pragma unroll
            for (int r = 0; r < 4; ++r) acc[mt][nt][r] += cv[nt];

    const float scale = 0.029462782549439484f;  // 1/sqrt(1152)

    // softmax: per-wave max over its 64 cols -> red[row][wave]
#pragma unroll
    for (int mt = 0; mt < 4; ++mt)
#pragma unroll
        for (int r = 0; r < 4; ++r) {
            float pm = fmaxf(fmaxf(acc[mt][0][r], acc[mt][1][r]),
                             fmaxf(acc[mt][2][r], acc[mt][3][r]));
#pragma unroll
            for (int off = 1; off <= 8; off <<= 1) pm = fmaxf(pm, __shfl_xor(pm, off));
            if (l16 == 0) red[mt * 16 + quad * 4 + r][wave] = pm;
        }
    __syncthreads();
#pragma unroll
    for (int mt = 0; mt < 4; ++mt)
#pragma unroll
        for (int r = 0; r < 4; ++r) {
            const int R = mt * 16 + quad * 4 + r;
            float4 q = *(const float4*)red[R];
            float m = fmaxf(fmaxf(q.x, q.y), fmaxf(q.z, q.w));
            float ps = 0.0f;
#pragma unroll
            for (int nt = 0; nt < 4; ++nt) {
                float e = __expf((acc[mt][nt][r] - m) * scale);
                acc[mt][nt][r] = e;
                ps += e;
            }
#pragma unroll
            for (int off = 1; off <= 8; off <<= 1) ps += __shfl_xor(ps, off);
            if (l16 == 0) red2[R][wave] = ps;
        }
    __syncthreads();
#pragma unroll
    for (int mt = 0; mt < 4; ++mt)
#pragma unroll
        for (int r = 0; r < 4; ++r) {
            const int R = mt * 16 + quad * 4 + r;
            float4 q = *(const float4*)red2[R];
            float inv = 1.0f / (q.x + q.y + q.z + q.w);
#pragma unroll
            for (int nt = 0; nt < 4; ++nt)
                Ps[R][wN + nt * 16 + l16] = (bf16)(acc[mt][nt][r] * inv);
        }

    // PV: out rows = P rows, cols d. Wave: rows (wave>>1)*32, cols (wave&1)*64.
    const bf16* VWTb = VWT + b * 294912;
    const int wRow  = (wave >> 1) * 32;
    const int wCol2 = (wave & 1) * 64;
    const int rb2 = tid >> 2, cb2 = (tid & 3) * 8;
    const long orow0 = b * 1024 + bx * 64;

#pragma unroll 1
    for (int d0 = 0; d0 < 1152; d0 += 128) {
        f32x4 acc2[2][4] = {};
#pragma unroll 1
        for (int kk = 0; kk < 256; kk += 32) {
            __syncthreads();
            async_copy16(VWTb + (long)(d0 + rb2) * 256 + kk + cb2,
                         (char*)Bs + wave * 1024);
            async_copy16(VWTb + (long)(d0 + 64 + rb2) * 256 + kk + cb2,
                         (char*)Bs + 4096 + wave * 1024);
            __syncthreads();
            bf16x8 af2[2], bf2[4];
#pragma unroll
            for (int t = 0; t < 2; ++t)
                af2[t] = *(const bf16x8*)&Ps[wRow + t * 16 + l16][kk + quad * 8];
#pragma unroll
            for (int t = 0; t < 4; ++t)
                bf2[t] = *(const bf16x8*)(Bs + (wCol2 + t * 16 + l16) * 32 + quad * 8);
#pragma unroll
            for (int mt = 0; mt < 2; ++mt)
#pragma unroll
                for (int nt = 0; nt < 4; ++nt)
                    acc2[mt][nt] = __builtin_amdgcn_mfma_f32_16x16x32_bf16(
                        af2[mt], bf2[nt], acc2[mt][nt], 0, 0, 0);
        }
#pragma unroll
        for (int mt = 0; mt < 2; ++mt) {
            const long row = orow0 + wRow + mt * 16 + quad * 4;
#pragma unroll
            for (int nt = 0; nt < 4; ++nt) {
                const int col = d0 + wCol2 + nt * 16 + l16;
                const float bb = bo[col];
#pragma unroll
                for (int r = 0; r < 4; ++r)
                    out[(row + r) * 1152 + col] = acc2[mt][nt][r] + bb;
            }
        }
    }
}

// Weight prep: z=0..2 transpose+cvt {Wq->slot0, Wk->slot2, Wv->slot3}; z=3 plain Wo->slot1.
__global__ void cvt_w_k(const float* __restrict__ Wq, const float* __restrict__ Wk,
                        const float* __restrict__ Wv, const float* __restrict__ Wo,
                        bf16* __restrict__ dst) {
    const int z = blockIdx.z;
    const int tid = threadIdx.x;
    if (z == 3) {  // plain: 324 blocks x 256 thr x 4 float4 = 331776
        long i0 = ((long)(blockIdx.y * 18 + blockIdx.x) * 256 + tid) * 4;
        bf16* d = dst + 1327104;
#pragma unroll
        for (int p = 0; p < 4; ++p) {
            float4 v = ((const float4*)Wo)[i0 + p];
            bf16x4 o = {(bf16)v.x, (bf16)v.y, (bf16)v.z, (bf16)v.w};
            ((bf16x4*)d)[i0 + p] = o;
        }
        return;
    }
    __shared__ bf16 t[64][66];
    const float* src = z == 0 ? Wq : z == 1 ? Wk : Wv;
    bf16* d = dst + (long)(z == 0 ? 0 : z == 1 ? 2 : 3) * 1327104;
    const int r0 = blockIdx.y * 64, c0 = blockIdx.x * 64;
    {
        int row = tid >> 4;
        int col4 = (tid & 15) * 4;
#pragma unroll
        for (int p = 0; p < 4; ++p) {
            int r = row + p * 16;
            float4 v = *(const float4*)(src + (long)(r0 + r) * 1152 + c0 + col4);
            t[col4 + 0][r] = (bf16)v.x;
            t[col4 + 1][r] = (bf16)v.y;
            t[col4 + 2][r] = (bf16)v.z;
            t[col4 + 3][r] = (bf16)v.w;
        }
    }
    __syncthreads();
    {
        int orow = tid >> 2;
        int oc = (tid & 3) * 16;
        bf16x8 a, b2;
#pragma unroll
        for (int j = 0; j < 8; ++j) { a[j] = t[orow][oc + j]; b2[j] = t[orow][oc + 8 + j]; }
        bf16* o = d + (long)(c0 + orow) * 1152 + r0 + oc;
        *(bf16x8*)o = a;
        *(bf16x8*)(o + 8) = b2;
    }
}

// y=0: vk = WkT·bq, zero biasUV[0:1152]; y=1: biasUV[1152:] = Wo·bv. One wave/row.
__global__ void rowdot2_k(const bf16* __restrict__ WkT, const bf16* __restrict__ Wo,
                          const float* __restrict__ bq, const float* __restrict__ bv,
                          float* __restrict__ vk, float* __restrict__ biasUV) {
    const int row = blockIdx.x * 4 + (threadIdx.x >> 6);
    const int lane = threadIdx.x & 63;
    const bf16* M = blockIdx.y == 0 ? WkT : Wo;
    const float* v = blockIdx.y == 0 ? bq : bv;
    const bf16* mr = M + (long)row * 1152;
    float acc = 0.0f;
#pragma unroll
    for (int j = 0; j < 18; ++j)
        acc += (float)mr[j * 64 + lane] * v[j * 64 + lane];
#pragma unroll
    for (int off = 32; off; off >>= 1) acc += __shfl_xor(acc, off, 64);
    if (lane == 0) {
        if (blockIdx.y == 0) { vk[row] = acc; biasUV[row] = 0.0f; }
        else biasUV[1152 + row] = acc;
    }
}

// out[row] = dot(M[row,0:1152], v). One wave per row.
__global__ void rowdot_k(const bf16* __restrict__ M, const float* __restrict__ v,
                         float* __restrict__ out) {
    const int row = blockIdx.x * 4 + (threadIdx.x >> 6);
    const int lane = threadIdx.x & 63;
    const bf16* mr = M + (long)row * 1152;
    float acc = 0.0f;
#pragma unroll
    for (int j = 0; j < 18; ++j)
        acc += (float)mr[j * 64 + lane] * v[j * 64 + lane];
#pragma unroll
    for (int off = 32; off; off >>= 1) acc += __shfl_xor(acc, off, 64);
    if (lane == 0) out[row] = acc;
}

// x fp32 [32768 x 1152] -> xb bf16 (all rows) + xm bf16 (mean over 4-row windows)
__global__ void cvt_merge_x_k(const float* __restrict__ x, bf16* __restrict__ xb,
                              bf16* __restrict__ xm) {
    int i = blockIdx.x * 256 + threadIdx.x;  // 8192*288 exact
    int w = i / 288;
    int c4 = i - w * 288;
    const float4* p = (const float4*)(x + (long)w * 4608) + c4;
    float4 a = p[0], b = p[288], c = p[576], d = p[864];
    bf16x4 oa = {(bf16)a.x, (bf16)a.y, (bf16)a.z, (bf16)a.w};
    bf16x4 ob = {(bf16)b.x, (bf16)b.y, (bf16)b.z, (bf16)b.w};
    bf16x4 oc = {(bf16)c.x, (bf16)c.y, (bf16)c.z, (bf16)c.w};
    bf16x4 od = {(bf16)d.x, (bf16)d.y, (bf16)d.z, (bf16)d.w};
    bf16* base = xb + (long)w * 4608 + c4 * 4;
    *(bf16x4*)(base)        = oa;
    *(bf16x4*)(base + 1152) = ob;
    *(bf16x4*)(base + 2304) = oc;
    *(bf16x4*)(base + 3456) = od;
    float4 s;
    s.x = (a.x + b.x + c.x + d.x) * 0.25f;
    s.y = (a.y + b.y + c.y + d.y) * 0.25f;
    s.z = (a.z + b.z + c.z + d.z) * 0.25f;
    s.w = (a.w + b.w + c.w + d.w) * 0.25f;
    bf16x4 o = {(bf16)s.x, (bf16)s.y, (bf16)s.z, (bf16)s.w};
    *(bf16x4*)(xm + (long)w * 1152 + c4 * 4) = o;
}

// VW part of UVW [b*256+m][2304]@+1152 -> VWT:[b][1152][256]
__global__ void transpose_vm_k(const bf16* __restrict__ UVW, bf16* __restrict__ VT) {
    __shared__ bf16 t[64][65];
    const int tid = threadIdx.x;
    const int b = blockIdx.z;
    const int d0 = blockIdx.x * 64, m0 = blockIdx.y * 64;
#pragma unroll
    for (int p = 0; p < 2; ++p) {
        int r = (tid >> 3) + p * 32;
        int c = (tid & 7) * 8;
        bf16x8 v = *(const bf16x8*)(UVW + (long)(b * 256 + m0 + r) * 2304 + 1152 + d0 + c);
#pragma unroll
        for (int j = 0; j < 8; ++j) t[c + j][r] = v[j];
    }
    __syncthreads();
#pragma unroll
    for (int p = 0; p < 2; ++p) {
        int r = (tid >> 3) + p * 32;
        int c = (tid & 7) * 8;
        bf16x8 o;
#pragma unroll
        for (int j = 0; j < 8; ++j) o[j] = t[r][c + j];
        *(bf16x8*)(VT + (long)b * 294912 + (long)(d0 + r) * 256 + m0 + c) = o;
    }
}

extern "C" void kernel_launch(void* const* d_in, const int* in_sizes, int n_in,
                              void* d_out, int out_size, void* d_ws, size_t ws_size,
                              hipStream_t stream) {
    const float* x  = (const float*)d_in[0];
    const float* Wq = (const float*)d_in[1];
    const float* bq = (const float*)d_in[2];
    const float* Wk = (const float*)d_in[3];
    const float* bk = (const float*)d_in[4];  (void)bk;  // softmax-invariant
    const float* Wv = (const float*)d_in[5];
    const float* bv = (const float*)d_in[6];
    const float* Wo = (const float*)d_in[7];
    const float* bo = (const float*)d_in[8];
    float* out = (float*)d_out;
    char* ws = (char*)d_ws;

    // ws layout (137.5 MB peak):
    //   [0, 75.5MB): WT4 (10.6MB, weight-prep phase) -> later overwritten by x_b
    bf16* WT4   = (bf16*)ws;                     // slots: WqT | Wo | WkT | WvT
    bf16* WkT_b = WT4 + 2 * 1327104;
    bf16* Wo_b  = WT4 + 1 * 1327104;
    bf16* x_b   = (bf16*)ws;                     // 75,497,472 B (after weight prep)
    bf16* WQK2  = (bf16*)(ws + 75497472);        // [2304x1152], 5,308,416 B
    float* biasUV = (float*)(ws + 80805888);     // [2304]
    float* vk     = (float*)(ws + 80815104);     // [1152]
    float* cvec   = (float*)(ws + 80819712);     // [8192]
    bf16* UVW   = (bf16*)(ws + 80852480);        // [8192x2304], 37,748,736 B
    bf16* VWT   = (bf16*)(ws + 118601216);       // [32][1152][256], 18,874,368 B

    // d_out scratch: xm dead before fused_attn writes out.
    bf16* xm_b = (bf16*)d_out;                   // [8192x1152], 18,874,368 B

    // 1. weight prep (WT4 lives only through step 3)
    cvt_w_k<<<dim3(18, 18, 4), 256, 0, stream>>>(Wq, Wk, Wv, Wo, WT4);

    // 2. Wqk = Wq^T·Wk (z=0); Wvo = Wo·Wv (z=1)
    gemm_bt<bf16, false><<<dim3(9, 9, 2), 256, 0, stream>>>(
        WT4, WkT_b, nullptr, WQK2,
        1152, 1152, 1152, 1152, 1152, 1.0f, 1327104, 1327104, 1327104);

    // 3. vk = WkT·bq (+ zero biasUV U-half); biasUV[1152:] = Wo·bv
    rowdot2_k<<<dim3(288, 2), 256, 0, stream>>>(WkT_b, Wo_b, bq, bv, vk, biasUV);

    // 4. x -> x_b (ws, overwrites WT4) + xm (d_out scratch)
    cvt_merge_x_k<<<9216, 256, 0, stream>>>(x, x_b, xm_b);

    // 5. [U | VW] = x_m @ WQK2^T + biasUV
    gemm_bt<bf16, true><<<dim3(18, 64, 1), 256, 0, stream>>>(
        xm_b, WQK2, biasUV, UVW, 2304, 1152, 1152, 1152, 2304, 1.0f, 0, 0, 0);

    // 6. c[m] = x_m · vk
    rowdot_k<<<2048, 256, 0, stream>>>(xm_b, vk, cvec);

    // 7. VWT = transpose(VW) per batch
    transpose_vm_k<<<dim3(18, 4, 32), 256, 0, stream>>>(UVW, VWT);

    // 8. fused: P = softmax((x@U^T + c)/sqrt(D)); out = P@VW + bo
    fused_attn_k<<<dim3(16, 32), 256, 0, stream>>>(x_b, UVW, VWT, cvec, bo, out);
}